// Round 3
// baseline (1466.018 us; speedup 1.0000x reference)
//
#include <hip/hip_runtime.h>

#define NHEADS 8
#define NNODES 100000
#define SLICE_NODES 2000
#define NSLICES 50            // ceil(NNODES / SLICE_NODES)
#define NCHUNK 10             // edge chunks
#define SLICE_F (SLICE_NODES * NHEADS)   // 16000 floats = 64000 B
#define NSUM_OFF 64           // float offset of node_sum within ws

// ---- order-preserving float<->uint encoding for atomicMax on signed floats
__device__ __forceinline__ unsigned fenc(float f) {
    unsigned u = __float_as_uint(f);
    return (u & 0x80000000u) ? ~u : (u | 0x80000000u);
}
__device__ __forceinline__ float fdec(unsigned u) {
    unsigned b = (u & 0x80000000u) ? (u ^ 0x80000000u) : ~u;
    return __uint_as_float(b);
}

// ---- pass 1: per-head max over edge_val [E,8], processed as float4 pairs
__global__ void __launch_bounds__(256) kmax(const float4* __restrict__ ev4,
                                            long long n4,
                                            unsigned* __restrict__ gmax) {
    const float NEG = -3.402823466e38f;
    float4 mv = make_float4(NEG, NEG, NEG, NEG);
    long long tid = blockIdx.x * (long long)blockDim.x + threadIdx.x;
    long long stride = (long long)gridDim.x * blockDim.x;
    for (long long i = tid; i < n4; i += stride) {
        float4 v = ev4[i];
        mv.x = fmaxf(mv.x, v.x);
        mv.y = fmaxf(mv.y, v.y);
        mv.z = fmaxf(mv.z, v.z);
        mv.w = fmaxf(mv.w, v.w);
    }
    float4 ov;
    ov.x = __shfl_xor(mv.x, 1);
    ov.y = __shfl_xor(mv.y, 1);
    ov.z = __shfl_xor(mv.z, 1);
    ov.w = __shfl_xor(mv.w, 1);
    float m8[8];
    if ((tid & 1) == 0) {
        m8[0] = mv.x; m8[1] = mv.y; m8[2] = mv.z; m8[3] = mv.w;
        m8[4] = ov.x; m8[5] = ov.y; m8[6] = ov.z; m8[7] = ov.w;
    } else {
        m8[0] = ov.x; m8[1] = ov.y; m8[2] = ov.z; m8[3] = ov.w;
        m8[4] = mv.x; m8[5] = mv.y; m8[6] = mv.z; m8[7] = mv.w;
    }
#pragma unroll
    for (int h = 0; h < 8; ++h) {
#pragma unroll
        for (int off = 2; off < 64; off <<= 1)
            m8[h] = fmaxf(m8[h], __shfl_xor(m8[h], off));
    }
    __shared__ float sm[4][8];
    int wid = threadIdx.x >> 6;
    int lane = threadIdx.x & 63;
    if (lane == 0) {
#pragma unroll
        for (int h = 0; h < 8; ++h) sm[wid][h] = m8[h];
    }
    __syncthreads();
    if (threadIdx.x < 8) {
        float v = sm[0][threadIdx.x];
#pragma unroll
        for (int w = 1; w < 4; ++w) v = fmaxf(v, sm[w][threadIdx.x]);
        atomicMax(&gmax[threadIdx.x], fenc(v));
    }
}

// ---- pass 1b: scale[h] = 0.5^k, k per reference formula
__global__ void kscale(const unsigned* __restrict__ gmax, float* __restrict__ scale) {
    int h = threadIdx.x;
    if (h < NHEADS) {
        float m = fdec(gmax[h]);
        float k = (m > 10.0f) ? ceilf(log2f(fmaxf(m, 1e-30f) / 10.0f)) : 0.0f;
        k = fmaxf(k, 0.0f);
        scale[h] = exp2f(-k);
    }
}

// ---- pass 2: node-sliced scan. Block (s,j): scan edge chunk j, accumulate
// exp(edge_val*scale) for rows in slice s into LDS, dump partial to global.
__global__ void __launch_bounds__(256) kscan(const float* __restrict__ ev,
                                             const int* __restrict__ row,
                                             const float* __restrict__ scale,
                                             float* __restrict__ partials,
                                             long long E, long long epc) {
    __shared__ float sm[SLICE_F];  // 64000 B
    int s = blockIdx.x / NCHUNK;
    int j = blockIdx.x % NCHUNK;
    int nodeBase = s * SLICE_NODES;

    for (int i = threadIdx.x; i < SLICE_F; i += 256) sm[i] = 0.0f;
    float s8[NHEADS];
#pragma unroll
    for (int h = 0; h < NHEADS; ++h) s8[h] = scale[h];
    __syncthreads();

    long long e0 = (long long)j * epc;
    long long e1 = e0 + epc;
    if (e1 > E) e1 = E;
    if (e0 >= e1) { /* empty chunk */ }
    long long nrows = e1 - e0;
    long long n4r = nrows >> 2;  // e0 is a multiple of 4 when epc is
    const int4* row4 = (const int4*)(row + e0);

    for (long long i = threadIdx.x; i < n4r; i += 256) {
        int4 r4 = row4[i];
        long long eb = e0 + (i << 2);
        int rr[4] = {r4.x, r4.y, r4.z, r4.w};
#pragma unroll
        for (int k = 0; k < 4; ++k) {
            int lr = rr[k] - nodeBase;
            if ((unsigned)lr < SLICE_NODES) {
                const float4* evp = (const float4*)(ev + (eb + k) * NHEADS);
                float4 a = evp[0], b = evp[1];
                float* dst = sm + lr * NHEADS;
                atomicAdd(dst + 0, expf(a.x * s8[0]));
                atomicAdd(dst + 1, expf(a.y * s8[1]));
                atomicAdd(dst + 2, expf(a.z * s8[2]));
                atomicAdd(dst + 3, expf(a.w * s8[3]));
                atomicAdd(dst + 4, expf(b.x * s8[4]));
                atomicAdd(dst + 5, expf(b.y * s8[5]));
                atomicAdd(dst + 6, expf(b.z * s8[6]));
                atomicAdd(dst + 7, expf(b.w * s8[7]));
            }
        }
    }
    // scalar tail (generic safety; empty for 6.4M/10 chunks)
    for (long long e = e0 + (n4r << 2) + threadIdx.x; e < e1; e += 256) {
        int lr = row[e] - nodeBase;
        if ((unsigned)lr < SLICE_NODES) {
            const float4* evp = (const float4*)(ev + e * NHEADS);
            float4 a = evp[0], b = evp[1];
            float* dst = sm + lr * NHEADS;
            atomicAdd(dst + 0, expf(a.x * s8[0]));
            atomicAdd(dst + 1, expf(a.y * s8[1]));
            atomicAdd(dst + 2, expf(a.z * s8[2]));
            atomicAdd(dst + 3, expf(a.w * s8[3]));
            atomicAdd(dst + 4, expf(b.x * s8[4]));
            atomicAdd(dst + 5, expf(b.y * s8[5]));
            atomicAdd(dst + 6, expf(b.z * s8[6]));
            atomicAdd(dst + 7, expf(b.w * s8[7]));
        }
    }
    __syncthreads();

    float4* outp = (float4*)(partials + (long long)blockIdx.x * SLICE_F);
    const float4* smp = (const float4*)sm;
    for (int i = threadIdx.x; i < SLICE_F / 4; i += 256) outp[i] = smp[i];
}

// ---- pass 2b: nsum = sum over NCHUNK partials per slice.
// partials flat layout: block (s*NCHUNK+j) wrote slice s => slice-major ==
// node-major, so nsum float4 index i4: s = i4/4000, l4 = i4%4000.
__global__ void __launch_bounds__(256) kreduce(const float4* __restrict__ partials,
                                               float4* __restrict__ nsum,
                                               int n4sum) {
    int i = blockIdx.x * blockDim.x + threadIdx.x;
    if (i >= n4sum) return;
    const int S4 = SLICE_F / 4;  // 4000
    int s = i / S4;
    int l4 = i - s * S4;
    const float4* base = partials + (long long)(s * NCHUNK) * S4 + l4;
    float4 acc = base[0];
#pragma unroll
    for (int j = 1; j < NCHUNK; ++j) {
        float4 v = base[(long long)j * S4];
        acc.x += v.x; acc.y += v.y; acc.z += v.z; acc.w += v.w;
    }
    nsum[i] = acc;
}

// ---- pass 3: out = exp(edge_val*scale) / node_sum[row]
__global__ void __launch_bounds__(256) kout(const float4* __restrict__ ev4,
                                            const int* __restrict__ row,
                                            const float* __restrict__ scale,
                                            const float* __restrict__ nsum,
                                            float4* __restrict__ out4,
                                            long long n4) {
    float4 sLo = *(const float4*)scale;
    float4 sHi = *(const float4*)(scale + 4);
    long long tid = blockIdx.x * (long long)blockDim.x + threadIdx.x;
    long long stride = (long long)gridDim.x * blockDim.x;
    for (long long i = tid; i < n4; i += stride) {
        float4 v = ev4[i];
        long long e = i >> 1;
        int hb = ((int)i & 1) << 2;
        int r = row[e];
        float4 s = (i & 1) ? sHi : sLo;
        const float4 ns = *(const float4*)(nsum + (long long)r * NHEADS + hb);
        float4 o;
        o.x = expf(v.x * s.x) / ns.x;
        o.y = expf(v.y * s.y) / ns.y;
        o.z = expf(v.z * s.z) / ns.z;
        o.w = expf(v.w * s.w) / ns.w;
        out4[i] = o;
    }
}

extern "C" void kernel_launch(void* const* d_in, const int* in_sizes, int n_in,
                              void* d_out, int out_size, void* d_ws, size_t ws_size,
                              hipStream_t stream) {
    const float* ev = (const float*)d_in[0];
    const int* row = (const int*)d_in[1];
    long long nElem = (long long)in_sizes[0];        // E * 8
    long long E = nElem / NHEADS;
    long long n4 = nElem >> 2;                       // float4 count
    long long epc = ((E + NCHUNK - 1) / NCHUNK + 3) & ~3LL;  // edges/chunk, mult of 4

    float* ws = (float*)d_ws;
    unsigned* gmax = (unsigned*)ws;   // [8]  encoded maxes
    float* scale = ws + 8;            // [8]
    float* nsum = ws + NSUM_OFF;      // [NNODES*8], fully written by kreduce

    // partial tables (NSLICES*NCHUNK*64KB = 32 MB) live in d_out scratch;
    // fully overwritten by kout afterwards.
    float* partials = (float*)d_out;

    // reset the atomicMax slots every call (ws not re-poisoned between replays)
    hipMemsetAsync(d_ws, 0, NSUM_OFF * sizeof(float), stream);

    kmax<<<1024, 256, 0, stream>>>((const float4*)ev, n4, gmax);
    kscale<<<1, 64, 0, stream>>>(gmax, scale);
    kscan<<<NSLICES * NCHUNK, 256, 0, stream>>>(ev, row, scale, partials, E, epc);
    kreduce<<<(NNODES * NHEADS / 4 + 255) / 256, 256, 0, stream>>>(
        (const float4*)partials, (float4*)nsum, NNODES * NHEADS / 4);
    kout<<<4096, 256, 0, stream>>>((const float4*)ev, row, scale, nsum, (float4*)d_out, n4);
}

// Round 4
// 579.985 us; speedup vs baseline: 2.5277x; 2.5277x over previous
//
#include <hip/hip_runtime.h>

#define NHEADS 8
#define NNODES 100000
#define SLICE_NODES 1000
#define NSLICES 100
#define NCHUNK 16
#define SLICE_F (SLICE_NODES * NHEADS)   // 8000 floats = 32 KB
#define NBLK 2048                        // blocks for prep/scatter passes
#define WS_NSUM_OFF 512                  // float offset of nsum in ws

// ws float layout: [0:8) gmax, [8:16) scale, [16:116) gcount, [116:216) goff,
//                  [216:316) resv, [512: 512+800000) nsum

// ---- order-preserving float<->uint encoding for atomicMax on signed floats
__device__ __forceinline__ unsigned fenc(float f) {
    unsigned u = __float_as_uint(f);
    return (u & 0x80000000u) ? ~u : (u | 0x80000000u);
}
__device__ __forceinline__ float fdec(unsigned u) {
    unsigned b = (u & 0x80000000u) ? (u ^ 0x80000000u) : ~u;
    return __uint_as_float(b);
}

// ---- pass A: per-head max + per-slice histogram, one streaming read of ev+row
__global__ void __launch_bounds__(256) kprep(const float4* __restrict__ ev4,
                                             const int* __restrict__ row,
                                             long long E, long long epb,
                                             unsigned* __restrict__ gmax,
                                             unsigned* __restrict__ gcount) {
    __shared__ unsigned hist[NSLICES];
    for (int i = threadIdx.x; i < NSLICES; i += 256) hist[i] = 0;
    __syncthreads();

    long long e0 = (long long)blockIdx.x * epb;
    long long e1 = e0 + epb;
    if (e1 > E) e1 = E;

    const float NEG = -3.402823466e38f;
    float m8[8];
#pragma unroll
    for (int h = 0; h < 8; ++h) m8[h] = NEG;

    for (long long e = e0 + threadIdx.x; e < e1; e += 256) {
        float4 a = ev4[e * 2];
        float4 b = ev4[e * 2 + 1];
        m8[0] = fmaxf(m8[0], a.x); m8[1] = fmaxf(m8[1], a.y);
        m8[2] = fmaxf(m8[2], a.z); m8[3] = fmaxf(m8[3], a.w);
        m8[4] = fmaxf(m8[4], b.x); m8[5] = fmaxf(m8[5], b.y);
        m8[6] = fmaxf(m8[6], b.z); m8[7] = fmaxf(m8[7], b.w);
        atomicAdd(&hist[(unsigned)row[e] / SLICE_NODES], 1u);
    }
    __syncthreads();
    for (int i = threadIdx.x; i < NSLICES; i += 256)
        if (hist[i]) atomicAdd(&gcount[i], hist[i]);

    // wave reduce the 8 maxima, then block reduce via LDS
#pragma unroll
    for (int h = 0; h < 8; ++h) {
#pragma unroll
        for (int off = 1; off < 64; off <<= 1)
            m8[h] = fmaxf(m8[h], __shfl_xor(m8[h], off));
    }
    __shared__ float sm[4][8];
    int wid = threadIdx.x >> 6;
    int lane = threadIdx.x & 63;
    if (lane == 0) {
#pragma unroll
        for (int h = 0; h < 8; ++h) sm[wid][h] = m8[h];
    }
    __syncthreads();
    if (threadIdx.x < 8) {
        float v = sm[0][threadIdx.x];
#pragma unroll
        for (int w = 1; w < 4; ++w) v = fmaxf(v, sm[w][threadIdx.x]);
        atomicMax(&gmax[threadIdx.x], fenc(v));
    }
}

// ---- pass B: scale + exclusive scan of bin counts (tiny)
__global__ void kscan0(const unsigned* __restrict__ gmax,
                       float* __restrict__ scale,
                       const unsigned* __restrict__ gcount,
                       unsigned* __restrict__ goff,
                       unsigned* __restrict__ resv) {
    if (threadIdx.x < NHEADS) {
        float m = fdec(gmax[threadIdx.x]);
        float k = (m > 10.0f) ? ceilf(log2f(fmaxf(m, 1e-30f) / 10.0f)) : 0.0f;
        k = fmaxf(k, 0.0f);
        scale[threadIdx.x] = exp2f(-k);
    }
    if (threadIdx.x == 0) {
        unsigned off = 0;
        for (int b = 0; b < NSLICES; ++b) {
            goff[b] = off;
            resv[b] = off;
            off += gcount[b];
        }
    }
}

// ---- pass C: scatter (edge_idx,row) pairs into per-slice bins
__global__ void __launch_bounds__(256) kscat(const int* __restrict__ row,
                                             long long E, long long epb,
                                             unsigned* __restrict__ resv,
                                             int2* __restrict__ pairs) {
    __shared__ unsigned hist[NSLICES];
    __shared__ unsigned cur[NSLICES];
    for (int i = threadIdx.x; i < NSLICES; i += 256) hist[i] = 0;
    __syncthreads();

    long long e0 = (long long)blockIdx.x * epb;
    long long e1 = e0 + epb;
    if (e1 > E) e1 = E;

    for (long long e = e0 + threadIdx.x; e < e1; e += 256)
        atomicAdd(&hist[(unsigned)row[e] / SLICE_NODES], 1u);
    __syncthreads();
    for (int i = threadIdx.x; i < NSLICES; i += 256)
        cur[i] = hist[i] ? atomicAdd(&resv[i], hist[i]) : 0u;
    __syncthreads();
    for (long long e = e0 + threadIdx.x; e < e1; e += 256) {
        int r = row[e];
        unsigned s = (unsigned)r / SLICE_NODES;
        unsigned pos = atomicAdd(&cur[s], 1u);
        pairs[pos] = make_int2((int)e, r);
    }
}

// ---- pass D: dense per-slice accumulation in LDS
__global__ void __launch_bounds__(256) kproc(const float4* __restrict__ ev4,
                                             const int2* __restrict__ pairs,
                                             const float* __restrict__ scale,
                                             const unsigned* __restrict__ gcount,
                                             const unsigned* __restrict__ goff,
                                             float* __restrict__ partials) {
    __shared__ float sm[SLICE_F];  // 32 KB
    int s = blockIdx.x / NCHUNK;
    int c = blockIdx.x % NCHUNK;
    for (int i = threadIdx.x; i < SLICE_F; i += 256) sm[i] = 0.0f;
    float s8[NHEADS];
#pragma unroll
    for (int h = 0; h < NHEADS; ++h) s8[h] = scale[h];
    __syncthreads();

    unsigned cnt = gcount[s];
    unsigned base = goff[s];
    unsigned c0 = base + (unsigned)(((unsigned long long)cnt * c) / NCHUNK);
    unsigned c1 = base + (unsigned)(((unsigned long long)cnt * (c + 1)) / NCHUNK);

    for (unsigned i = c0 + threadIdx.x; i < c1; i += 256) {
        int2 p = pairs[i];
        const float4* evp = ev4 + (long long)p.x * 2;
        float4 a = evp[0], b = evp[1];
        float* dst = sm + (p.y - s * SLICE_NODES) * NHEADS;
        atomicAdd(dst + 0, expf(a.x * s8[0]));
        atomicAdd(dst + 1, expf(a.y * s8[1]));
        atomicAdd(dst + 2, expf(a.z * s8[2]));
        atomicAdd(dst + 3, expf(a.w * s8[3]));
        atomicAdd(dst + 4, expf(b.x * s8[4]));
        atomicAdd(dst + 5, expf(b.y * s8[5]));
        atomicAdd(dst + 6, expf(b.z * s8[6]));
        atomicAdd(dst + 7, expf(b.w * s8[7]));
    }
    __syncthreads();

    float4* op = (float4*)(partials + (long long)blockIdx.x * SLICE_F);
    const float4* sp = (const float4*)sm;
    for (int i = threadIdx.x; i < SLICE_F / 4; i += 256) op[i] = sp[i];
}

// ---- pass E: nsum = sum of NCHUNK partials per slice (slice-major == node-major)
__global__ void __launch_bounds__(256) kred(const float4* __restrict__ partials,
                                            float4* __restrict__ nsum,
                                            int n4sum) {
    int i = blockIdx.x * blockDim.x + threadIdx.x;
    if (i >= n4sum) return;
    const int S4 = SLICE_F / 4;  // 2000
    int s = i / S4;
    int l4 = i - s * S4;
    const float4* base = partials + (long long)(s * NCHUNK) * S4 + l4;
    float4 acc = base[0];
#pragma unroll
    for (int j = 1; j < NCHUNK; ++j) {
        float4 v = base[(long long)j * S4];
        acc.x += v.x; acc.y += v.y; acc.z += v.z; acc.w += v.w;
    }
    nsum[i] = acc;
}

// ---- pass F: out = exp(edge_val*scale) / nsum[row]
__global__ void __launch_bounds__(256) kout(const float4* __restrict__ ev4,
                                            const int* __restrict__ row,
                                            const float* __restrict__ scale,
                                            const float* __restrict__ nsum,
                                            float4* __restrict__ out4,
                                            long long n4) {
    float4 sLo = *(const float4*)scale;
    float4 sHi = *(const float4*)(scale + 4);
    long long tid = blockIdx.x * (long long)blockDim.x + threadIdx.x;
    long long stride = (long long)gridDim.x * blockDim.x;
    for (long long i = tid; i < n4; i += stride) {
        float4 v = ev4[i];
        long long e = i >> 1;
        int hb = ((int)i & 1) << 2;
        int r = row[e];
        float4 s = (i & 1) ? sHi : sLo;
        const float4 ns = *(const float4*)(nsum + (long long)r * NHEADS + hb);
        float4 o;
        o.x = expf(v.x * s.x) / ns.x;
        o.y = expf(v.y * s.y) / ns.y;
        o.z = expf(v.z * s.z) / ns.z;
        o.w = expf(v.w * s.w) / ns.w;
        out4[i] = o;
    }
}

extern "C" void kernel_launch(void* const* d_in, const int* in_sizes, int n_in,
                              void* d_out, int out_size, void* d_ws, size_t ws_size,
                              hipStream_t stream) {
    const float* ev = (const float*)d_in[0];
    const int* row = (const int*)d_in[1];
    long long nElem = (long long)in_sizes[0];  // E * 8
    long long E = nElem / NHEADS;
    long long n4 = nElem >> 2;
    long long epb = (E + NBLK - 1) / NBLK;

    float* ws = (float*)d_ws;
    unsigned* gmax = (unsigned*)ws;          // [8]
    float* scale = ws + 8;                   // [8]
    unsigned* gcount = (unsigned*)(ws + 16); // [100]
    unsigned* goff = (unsigned*)(ws + 116);  // [100]
    unsigned* resv = (unsigned*)(ws + 216);  // [100]
    float* nsum = ws + WS_NSUM_OFF;          // [800000]

    // scratch inside d_out (fully overwritten by kout at the end):
    int2* pairs = (int2*)d_out;                               // 6.4M * 8B = 51.2 MB
    float* partials = (float*)d_out + (E * 2);                // 100*16*32KB = 51.2 MB

    // zero gmax + gcount (ws is not re-poisoned between timed replays)
    hipMemsetAsync(d_ws, 0, WS_NSUM_OFF * sizeof(float), stream);

    kprep<<<NBLK, 256, 0, stream>>>((const float4*)ev, row, E, epb, gmax, gcount);
    kscan0<<<1, 128, 0, stream>>>(gmax, scale, gcount, goff, resv);
    kscat<<<NBLK, 256, 0, stream>>>(row, E, epb, resv, pairs);
    kproc<<<NSLICES * NCHUNK, 256, 0, stream>>>((const float4*)ev, pairs, scale,
                                                gcount, goff, partials);
    kred<<<(NNODES * NHEADS / 4 + 255) / 256, 256, 0, stream>>>(
        (const float4*)partials, (float4*)nsum, NNODES * NHEADS / 4);
    kout<<<4096, 256, 0, stream>>>((const float4*)ev, row, scale, nsum,
                                   (float4*)d_out, n4);
}